// Round 26
// baseline (143.122 us; speedup 1.0000x reference)
//
#include <hip/hip_runtime.h>
#include <math.h>

#define NFEAT 128
#define EPSBN 1e-5f
#define LDA 136   // bf16 elems per LDS row: 128 + 8 pad
#define NREP 8    // logit3 replicas to spread atomic contention
#define G1GRID 1536   // k1a grid

typedef __attribute__((ext_vector_type(8))) short short8;
typedef __attribute__((ext_vector_type(4))) float f32x4;

__device__ __forceinline__ unsigned short f2bf(float x) {
  union { float f; unsigned u; } v; v.f = x;
  unsigned r = v.u + 0x7FFF + ((v.u >> 16) & 1);   // RNE
  return (unsigned short)(r >> 16);
}
__device__ __forceinline__ float bf2f(unsigned short h) {
  union { unsigned u; float f; } v; v.u = (unsigned)h << 16;
  return v.f;
}

// ---------------------------------------------------------------------------
// KP: blocks 0..23: W' = (W + I) as bf16 in MFMA B-fragment order.
// Blocks 24..29: fold back-half into MT + cb.
//   logits = S@M1 + I@M3 + R@M4 + NB@M2 + cb
// MT layout: MT[cl*512 + part*128 + k], part: 0=S 1=I 2=R 3=NB.
// ---------------------------------------------------------------------------
__global__ __launch_bounds__(256) void kp_params(
    const float* __restrict__ Ws, const float* __restrict__ Wi,
    const float* __restrict__ Wr,
    const float* __restrict__ WtoI, const float* __restrict__ btoI,
    const float* __restrict__ WtoR, const float* __restrict__ btoR,
    const float* __restrict__ Wout, const float* __restrict__ bout,
    short* __restrict__ Whi,
    float* __restrict__ MT, float* __restrict__ cb)
{
  const int tid = threadIdx.x;
  if (blockIdx.x < 24) {
    int t = blockIdx.x * 256 + tid;   // 6144 total
    int m   = t >> 11;
    int rem = t & 2047;
    int kf  = rem >> 9;
    int kg  = (rem >> 7) & 3;
    int c   = rem & 127;
    const float* W = (m == 0) ? Ws : ((m == 1) ? Wi : Wr);
    short hb[8];
#pragma unroll
    for (int j = 0; j < 8; j++) {
      int k = kf * 32 + kg * 8 + j;
      float w = W[(size_t)k * NFEAT + c] + (k == c ? 1.0f : 0.0f);
      hb[j] = (short)f2bf(w);
    }
    int base = ((m * 16 + kf * 4 + kg) << 10) + (c << 3);
    *(short8*)&Whi[base] = *(short8*)hb;
    return;
  }

  int t = (blockIdx.x - 24) * 256 + tid;   // 0..1535
  int cl = t / 512;
  int idx = t - cl * 512;
  int part = idx >> 7, k = idx & 127;
  float val;
  if (part == 0) {            // S: Wo1 + WtoI_top @ (Wo2-Wo1)
    float s = Wout[k * 3 + cl];
    for (int f = 0; f < 128; f++)
      s = fmaf(WtoI[k * 128 + f],
               Wout[(128 + f) * 3 + cl] - Wout[f * 3 + cl], s);
    val = s;
  } else if (part == 1) {     // I: Wo2 + WtoR @ (Wo3-Wo2)
    float s = Wout[(128 + k) * 3 + cl];
    for (int f = 0; f < 128; f++)
      s = fmaf(WtoR[k * 128 + f],
               Wout[(256 + f) * 3 + cl] - Wout[(128 + f) * 3 + cl], s);
    val = s;
  } else if (part == 2) {     // R: Wo3
    val = Wout[(256 + k) * 3 + cl];
  } else {                    // NB: WtoI_bot @ (Wo2-Wo1)
    float s = 0.f;
    for (int f = 0; f < 128; f++)
      s = fmaf(WtoI[(128 + k) * 128 + f],
               Wout[(128 + f) * 3 + cl] - Wout[f * 3 + cl], s);
    val = s;
  }
  MT[cl * 512 + idx] = val;

  if (blockIdx.x == 24 && tid < 3) {
    float s = bout[tid];
    for (int f = 0; f < 128; f++) {
      s = fmaf(btoI[f], Wout[(128 + f) * 3 + tid] - Wout[f * 3 + tid], s);
      s = fmaf(btoR[f], Wout[(256 + f) * 3 + tid] - Wout[(128 + f) * 3 + tid], s);
    }
    cb[tid] = s;
  }
}

// ---------------------------------------------------------------------------
// K1a_store v5: plain-bf16 GEMM P_w = feat @ (W_w+I) + b_w.
// 256-thr blocks, 32-row tiles, grid 1536 (R23/R24: residency is
// scheduler-limited; 1536 is the sweet spot).  Stats via DIRECT
// unsafeAtomicAdd at block end — R25 ledger showed the Spart+k_red
// side-car cost ~8 us of serial latency-bound reduce; R21 proved
// hundreds of blocks' tail atomics are absorbed under the kernel.
// P stored as single bf16.  Natural VGPR (R6/R22 spill lesson).
// ---------------------------------------------------------------------------
__global__ __launch_bounds__(256) void k1a_store(
    const float* __restrict__ feat,
    const short* __restrict__ Whi,
    const float* __restrict__ bs, const float* __restrict__ bi,
    const float* __restrict__ br,
    float* __restrict__ stats,           // 768, pre-zeroed
    unsigned short* __restrict__ Pb,     // 3*N*128 bf16
    int N, int ntiles)
{
  __shared__ short Ah[32 * LDA];   // 8.7 KB

  const int tid  = threadIdx.x;
  const int lane = tid & 63;
  const int wv   = tid >> 6;          // 0..3
  const int l15  = lane & 15;
  const int kg   = lane >> 4;         // 0..3
  const int krow = kg * 8;
  const int sr   = tid >> 3;          // staging row 0..31
  const int so   = tid & 7;           // staging 16-float chunk

  const int col0 = wv * 32 + l15;
  const int col1 = wv * 32 + 16 + l15;

  float bias0[3], bias1[3];
  {
    const float* Bm[3] = {bs, bi, br};
#pragma unroll
    for (int m = 0; m < 3; m++) { bias0[m] = Bm[m][col0]; bias1[m] = Bm[m][col1]; }
  }
  float ssum0[3] = {0.f, 0.f, 0.f}, ssq0[3] = {0.f, 0.f, 0.f};
  float ssum1[3] = {0.f, 0.f, 0.f}, ssq1[3] = {0.f, 0.f, 0.f};
  const size_t nf = (size_t)N * NFEAT;

  for (int tile = blockIdx.x; tile < ntiles; tile += gridDim.x) {
    const int row0 = tile * 32;
    // ---- stage 32x128 tile as bf16
    {
      int gr = row0 + sr; if (gr >= N) gr = N - 1;
      const float4* s4 = (const float4*)(feat + (size_t)gr * NFEAT + so * 16);
      short hbuf[16];
#pragma unroll
      for (int q = 0; q < 4; q++) {
        float4 f = s4[q];
        float xs[4] = {f.x, f.y, f.z, f.w};
#pragma unroll
        for (int cc = 0; cc < 4; cc++) hbuf[q * 4 + cc] = (short)f2bf(xs[cc]);
      }
      *(short8*)&Ah[sr * LDA + so * 16]     = *(short8*)(hbuf);
      *(short8*)&Ah[sr * LDA + so * 16 + 8] = *(short8*)(hbuf + 8);
    }
    asm volatile("s_waitcnt lgkmcnt(0)" ::: "memory");
    __builtin_amdgcn_s_barrier();

    // ---- m-outer compute: 4 live accs, 48 MFMA/tile/wave
#pragma unroll
    for (int m = 0; m < 3; m++) {
      f32x4 a00 = {0.f,0.f,0.f,0.f}, a01 = {0.f,0.f,0.f,0.f};
      f32x4 a10 = {0.f,0.f,0.f,0.f}, a11 = {0.f,0.f,0.f,0.f};
#pragma unroll
      for (int kf = 0; kf < 4; kf++) {
        int fb0 = ((m * 16 + kf * 4 + kg) << 10) + (col0 << 3);
        int fb1 = ((m * 16 + kf * 4 + kg) << 10) + (col1 << 3);
        short8 b0 = *(const short8*)&Whi[fb0];
        short8 b1 = *(const short8*)&Whi[fb1];
        short8 ar0 = *(const short8*)&Ah[(l15) * LDA + kf * 32 + krow];
        short8 ar1 = *(const short8*)&Ah[(16 + l15) * LDA + kf * 32 + krow];
        a00 = __builtin_amdgcn_mfma_f32_16x16x32_bf16(ar0, b0, a00, 0, 0, 0);
        a01 = __builtin_amdgcn_mfma_f32_16x16x32_bf16(ar1, b0, a01, 0, 0, 0);
        a10 = __builtin_amdgcn_mfma_f32_16x16x32_bf16(ar0, b1, a10, 0, 0, 0);
        a11 = __builtin_amdgcn_mfma_f32_16x16x32_bf16(ar1, b1, a11, 0, 0, 0);
      }
      // epilogue for this m: bias, stats, bf16 store
#pragma unroll
      for (int g = 0; g < 4; g++) {
        int gr0 = row0 + kg * 4 + g;        // rf = 0
        int gr1 = row0 + 16 + kg * 4 + g;   // rf = 1
        if (gr0 < N) {
          float v = a00[g] + bias0[m];
          ssum0[m] += v; ssq0[m] += v * v;
          Pb[(size_t)m * nf + (size_t)gr0 * NFEAT + col0] = f2bf(v);
          float w = a10[g] + bias1[m];
          ssum1[m] += w; ssq1[m] += w * w;
          Pb[(size_t)m * nf + (size_t)gr0 * NFEAT + col1] = f2bf(w);
        }
        if (gr1 < N) {
          float v = a01[g] + bias0[m];
          ssum0[m] += v; ssq0[m] += v * v;
          Pb[(size_t)m * nf + (size_t)gr1 * NFEAT + col0] = f2bf(v);
          float w = a11[g] + bias1[m];
          ssum1[m] += w; ssq1[m] += w * w;
          Pb[(size_t)m * nf + (size_t)gr1 * NFEAT + col1] = f2bf(w);
        }
      }
    }
    asm volatile("s_waitcnt lgkmcnt(0)" ::: "memory");
    __builtin_amdgcn_s_barrier();
  }

  // ---- reduce over kg (lane bits 4-5), one atomic set per block
#pragma unroll
  for (int m = 0; m < 3; m++) {
    float s0 = ssum0[m], q0 = ssq0[m], s1 = ssum1[m], q1 = ssq1[m];
    s0 += __shfl_xor(s0, 16); s0 += __shfl_xor(s0, 32);
    q0 += __shfl_xor(q0, 16); q0 += __shfl_xor(q0, 32);
    s1 += __shfl_xor(s1, 16); s1 += __shfl_xor(s1, 32);
    q1 += __shfl_xor(q1, 16); q1 += __shfl_xor(q1, 32);
    if (kg == 0) {
      unsafeAtomicAdd(&stats[m * 256 + col0], s0);
      unsafeAtomicAdd(&stats[m * 256 + 128 + col0], q0);
      unsafeAtomicAdd(&stats[m * 256 + col1], s1);
      unsafeAtomicAdd(&stats[m * 256 + 128 + col1], q1);
    }
  }
}

// ---------------------------------------------------------------------------
// K1g: elementwise second-GEMM replacement.  Builds its swizzled A4s/B4s
// tables INLINE from stats/gamma/beta/MT.  16 lanes/row; per (row, m) one
// uint4 = 8 bf16 cols; conflict-free b128 LDS table reads;
// v = relu(a*P+kv); branchless q-accum.  Zeroes logit3R.
// 256-thr block: >256 LDS staging via strided loops (R17 lesson).
// ---------------------------------------------------------------------------
__global__ __launch_bounds__(256) void k1g_post(
    const unsigned short* __restrict__ Pb,
    const float* __restrict__ stats,
    const float* __restrict__ gamma, const float* __restrict__ beta,
    const float* __restrict__ MT,
    float* __restrict__ slogA, float* __restrict__ qv,
    float* __restrict__ logit3R, int N, int N4, int nrt, float invN)
{
  __shared__ float4 A4s[384];
  __shared__ float4 B4s[384];
  const int tid = threadIdx.x;
  for (int i = tid; i < 384; i += 256) {
    int m = i >> 7, c = i & 127;
    float mu = stats[m * 256 + c] * invN;
    float var = stats[m * 256 + 128 + c] * invN - mu * mu;
    float a = gamma[c] * rsqrtf(var + EPSBN);
    float kv = beta[c] - mu * a;
    int idx = m * 128 + (c & 7) * 16 + (c >> 3);
    A4s[idx] = make_float4(MT[0 * 512 + m * 128 + c],
                           MT[1 * 512 + m * 128 + c],
                           MT[2 * 512 + m * 128 + c], a);
    if (m == 1)
      B4s[idx] = make_float4(MT[0 * 512 + 384 + c],
                             MT[1 * 512 + 384 + c],
                             MT[2 * 512 + 384 + c], kv);
    else
      B4s[idx] = make_float4(0.f, 0.f, 0.f, kv);
  }
  __syncthreads();

  const int l15 = tid & 15;
  const int rg  = tid >> 4;
  const size_t nf = (size_t)N * NFEAT;

  for (int it = blockIdx.x; it < nrt; it += gridDim.x) {
    // zero logit3R for these 16 rows x NREP reps (128 float4; tid<128)
    if (tid < 128) {
      int rep = tid >> 4;
      int zr = it * 16 + (tid & 15);
      if (zr < N)
        *(float4*)&logit3R[(size_t)rep * N4 + (size_t)zr * 4] =
            make_float4(0.f, 0.f, 0.f, 0.f);
    }

    int row = it * 16 + rg;
    if (row >= N) continue;

    float s0 = 0.f, s1 = 0.f, s2 = 0.f;
    float q0 = 0.f, q1 = 0.f, q2 = 0.f;
#pragma unroll
    for (int m = 0; m < 3; m++) {
      const uint4* p4 =
          (const uint4*)(Pb + (size_t)m * nf + (size_t)row * NFEAT + l15 * 8);
      uint4 u = p4[0];
      unsigned dw[4] = {u.x, u.y, u.z, u.w};
#pragma unroll
      for (int d = 0; d < 4; d++) {
        {
          float4 ab = A4s[m * 128 + (2 * d) * 16 + l15];
          float4 bq = B4s[m * 128 + (2 * d) * 16 + l15];
          float P = bf2f((unsigned short)(dw[d] & 0xffffu));
          float v = fmaxf(fmaf(ab.w, P, bq.w), 0.f);
          s0 = fmaf(v, ab.x, s0); s1 = fmaf(v, ab.y, s1); s2 = fmaf(v, ab.z, s2);
          q0 = fmaf(v, bq.x, q0); q1 = fmaf(v, bq.y, q1); q2 = fmaf(v, bq.z, q2);
        }
        {
          float4 ab = A4s[m * 128 + (2 * d + 1) * 16 + l15];
          float4 bq = B4s[m * 128 + (2 * d + 1) * 16 + l15];
          float P = bf2f((unsigned short)(dw[d] >> 16));
          float v = fmaxf(fmaf(ab.w, P, bq.w), 0.f);
          s0 = fmaf(v, ab.x, s0); s1 = fmaf(v, ab.y, s1); s2 = fmaf(v, ab.z, s2);
          q0 = fmaf(v, bq.x, q0); q1 = fmaf(v, bq.y, q1); q2 = fmaf(v, bq.z, q2);
        }
      }
    }
#pragma unroll
    for (int off = 1; off < 16; off <<= 1) {
      s0 += __shfl_xor(s0, off); s1 += __shfl_xor(s1, off);
      s2 += __shfl_xor(s2, off);
      q0 += __shfl_xor(q0, off); q1 += __shfl_xor(q1, off);
      q2 += __shfl_xor(q2, off);
    }
    if (l15 == 0) {
      *(float4*)&slogA[(size_t)row * 4] = make_float4(s0, s1, s2, 0.f);
      *(float4*)&qv[(size_t)row * 4]    = make_float4(q0, q1, q2, 0.f);
    }
  }
}

// ---------------------------------------------------------------------------
// K_edge: 64 lanes = 21 edges x 3 comps; one atomic/lane, same-line merge,
// replica (waveID&7) spreads contention.
// ---------------------------------------------------------------------------
__global__ __launch_bounds__(256) void k_edge(
    const int* __restrict__ eidx, const float* __restrict__ ew,
    const float* __restrict__ q, float* __restrict__ logit3R,
    int E, int N4)
{
  const int wid  = (blockIdx.x * 256 + threadIdx.x) >> 6;
  const int lane = threadIdx.x & 63;
  const int el   = lane / 3;
  const int comp = lane - el * 3;
  if (el >= 21) return;
  const int e = wid * 21 + el;
  if (e >= E) return;

  int src = eidx[e];
  int dst = eidx[E + e];
  float w = ew[e];
  float qvv = q[(size_t)src * 4 + comp];
  int rep = wid & (NREP - 1);
  unsafeAtomicAdd(&logit3R[(size_t)rep * N4 + (size_t)dst * 4 + comp], qvv * w);
}

// ---------------------------------------------------------------------------
// K4t: out[r] = softmax(slog[r] + sum_rep logit3R[rep][r] + cb).
// ---------------------------------------------------------------------------
__global__ __launch_bounds__(256) void k4_final(
    const float* __restrict__ slogA, const float* __restrict__ logit3R,
    const float* __restrict__ cb,
    float* __restrict__ out, int N, int N4)
{
  int r = blockIdx.x * 256 + threadIdx.x;
  if (r >= N) return;
  float4 S = *(const float4*)&slogA[(size_t)r * 4];
  float l0 = S.x + cb[0], l1 = S.y + cb[1], l2 = S.z + cb[2];
#pragma unroll
  for (int rep = 0; rep < NREP; rep++) {
    float4 L = *(const float4*)&logit3R[(size_t)rep * N4 + (size_t)r * 4];
    l0 += L.x; l1 += L.y; l2 += L.z;
  }
  float mx = fmaxf(l0, fmaxf(l1, l2));
  float e0 = expf(l0 - mx), e1 = expf(l1 - mx), e2 = expf(l2 - mx);
  float inv = 1.f / (e0 + e1 + e2);
  out[(size_t)r * 3 + 0] = e0 * inv;
  out[(size_t)r * 3 + 1] = e1 * inv;
  out[(size_t)r * 3 + 2] = e2 * inv;
}

// ---------------------------------------------------------------------------
extern "C" void kernel_launch(void* const* d_in, const int* in_sizes, int n_in,
                              void* d_out, int out_size, void* d_ws, size_t ws_size,
                              hipStream_t stream)
{
  const float* feat  = (const float*)d_in[0];
  const int*   eidx  = (const int*)  d_in[1];
  const float* ew    = (const float*)d_in[2];
  const float* Ws    = (const float*)d_in[3];
  const float* bs    = (const float*)d_in[4];
  const float* Wi    = (const float*)d_in[5];
  const float* bi    = (const float*)d_in[6];
  const float* Wr    = (const float*)d_in[7];
  const float* br    = (const float*)d_in[8];
  const float* gamma = (const float*)d_in[9];
  const float* beta  = (const float*)d_in[10];
  const float* WtoI  = (const float*)d_in[11];
  const float* btoI  = (const float*)d_in[12];
  const float* WtoR  = (const float*)d_in[13];
  const float* btoR  = (const float*)d_in[14];
  const float* Wout  = (const float*)d_in[15];
  const float* bout  = (const float*)d_in[16];

  const int N = in_sizes[0] / NFEAT;
  const int E = in_sizes[2];
  const int N4 = 4 * N;
  const float invN = 1.0f / (float)N;
  float* out = (float*)d_out;

  float* logit3R = (float*)d_ws;                 // NREP*4*N
  float* slogA   = logit3R + (size_t)NREP * N4;  // 4*N
  float* qv      = slogA + 4 * (size_t)N;        // 4*N
  float* stats   = qv + 4 * (size_t)N;           // 768
  float* MT      = stats + 768;                  // 1536
  float* cb      = MT + 1536;                    // 4
  short* Whi     = (short*)(cb + 4);             // 49152
  unsigned short* Pb = (unsigned short*)(Whi + 49152);  // 3*N*128 bf16

  hipMemsetAsync(stats, 0, 768 * sizeof(float), stream);

  const int nt32 = (N + 31) / 32;         // 3125
  const int nrt  = (N + 15) / 16;         // 6250

  kp_params<<<30, 256, 0, stream>>>(Ws, Wi, Wr, WtoI, btoI, WtoR, btoR,
                                    Wout, bout, Whi, MT, cb);
  k1a_store<<<G1GRID, 256, 0, stream>>>(feat, Whi, bs, bi, br, stats, Pb,
                                        N, nt32);
  k1g_post<<<2048, 256, 0, stream>>>(Pb, stats, gamma, beta, MT,
                                     slogA, qv, logit3R, N, N4, nrt, invN);
  const int nwaves = (E + 20) / 21;
  k_edge<<<(nwaves + 3) / 4, 256, 0, stream>>>(eidx, ew, qv, logit3R, E, N4);
  k4_final<<<(N + 255) / 256, 256, 0, stream>>>(slogA, logit3R, cb, out, N, N4);
}

// Round 27
// 120.597 us; speedup vs baseline: 1.1868x; 1.1868x over previous
//
#include <hip/hip_runtime.h>
#include <math.h>

#define NFEAT 128
#define EPSBN 1e-5f
#define LDA 136   // bf16 elems per LDS row: 128 + 8 pad
#define NREP 8    // logit3 replicas to spread atomic contention
#define G1GRID 1536   // k1a grid; k_redbn assumes G1GRID % 256 == 0

typedef __attribute__((ext_vector_type(8))) short short8;
typedef __attribute__((ext_vector_type(4))) float f32x4;

__device__ __forceinline__ unsigned short f2bf(float x) {
  union { float f; unsigned u; } v; v.f = x;
  unsigned r = v.u + 0x7FFF + ((v.u >> 16) & 1);   // RNE
  return (unsigned short)(r >> 16);
}
__device__ __forceinline__ float bf2f(unsigned short h) {
  union { unsigned u; float f; } v; v.u = (unsigned)h << 16;
  return v.f;
}

// ---------------------------------------------------------------------------
// KP: blocks 0..23: W' = (W + I) as bf16 in MFMA B-fragment order.
// Blocks 24..29: fold back-half into MT + cb.
//   logits = S@M1 + I@M3 + R@M4 + NB@M2 + cb
// MT layout: MT[cl*512 + part*128 + k], part: 0=S 1=I 2=R 3=NB.
// ---------------------------------------------------------------------------
__global__ __launch_bounds__(256) void kp_params(
    const float* __restrict__ Ws, const float* __restrict__ Wi,
    const float* __restrict__ Wr,
    const float* __restrict__ WtoI, const float* __restrict__ btoI,
    const float* __restrict__ WtoR, const float* __restrict__ btoR,
    const float* __restrict__ Wout, const float* __restrict__ bout,
    short* __restrict__ Whi,
    float* __restrict__ MT, float* __restrict__ cb)
{
  const int tid = threadIdx.x;
  if (blockIdx.x < 24) {
    int t = blockIdx.x * 256 + tid;   // 6144 total
    int m   = t >> 11;
    int rem = t & 2047;
    int kf  = rem >> 9;
    int kg  = (rem >> 7) & 3;
    int c   = rem & 127;
    const float* W = (m == 0) ? Ws : ((m == 1) ? Wi : Wr);
    short hb[8];
#pragma unroll
    for (int j = 0; j < 8; j++) {
      int k = kf * 32 + kg * 8 + j;
      float w = W[(size_t)k * NFEAT + c] + (k == c ? 1.0f : 0.0f);
      hb[j] = (short)f2bf(w);
    }
    int base = ((m * 16 + kf * 4 + kg) << 10) + (c << 3);
    *(short8*)&Whi[base] = *(short8*)hb;
    return;
  }

  int t = (blockIdx.x - 24) * 256 + tid;   // 0..1535
  int cl = t / 512;
  int idx = t - cl * 512;
  int part = idx >> 7, k = idx & 127;
  float val;
  if (part == 0) {            // S: Wo1 + WtoI_top @ (Wo2-Wo1)
    float s = Wout[k * 3 + cl];
    for (int f = 0; f < 128; f++)
      s = fmaf(WtoI[k * 128 + f],
               Wout[(128 + f) * 3 + cl] - Wout[f * 3 + cl], s);
    val = s;
  } else if (part == 1) {     // I: Wo2 + WtoR @ (Wo3-Wo2)
    float s = Wout[(128 + k) * 3 + cl];
    for (int f = 0; f < 128; f++)
      s = fmaf(WtoR[k * 128 + f],
               Wout[(256 + f) * 3 + cl] - Wout[(128 + f) * 3 + cl], s);
    val = s;
  } else if (part == 2) {     // R: Wo3
    val = Wout[(256 + k) * 3 + cl];
  } else {                    // NB: WtoI_bot @ (Wo2-Wo1)
    float s = 0.f;
    for (int f = 0; f < 128; f++)
      s = fmaf(WtoI[(128 + k) * 128 + f],
               Wout[(128 + f) * 3 + cl] - Wout[f * 3 + cl], s);
    val = s;
  }
  MT[cl * 512 + idx] = val;

  if (blockIdx.x == 24 && tid < 3) {
    float s = bout[tid];
    for (int f = 0; f < 128; f++) {
      s = fmaf(btoI[f], Wout[(128 + f) * 3 + tid] - Wout[f * 3 + tid], s);
      s = fmaf(btoR[f], Wout[(256 + f) * 3 + tid] - Wout[(128 + f) * 3 + tid], s);
    }
    cb[tid] = s;
  }
}

// ---------------------------------------------------------------------------
// K1a_store v6: plain-bf16 GEMM P_w = feat @ (W_w+I) + b_w.
// 256-thr blocks, 32-row tiles, grid 1536 (R23-proven 46 us config).
// Stats -> per-block partials written TRANSPOSED (SpartT[idx][bid]) so the
// reducer reads coalesced.  Direct atomics REFUTED by R26 (+20 us: 1536
// bursty contributions per address serialize at the coherence point).
// P stored as single bf16.  Natural VGPR (R6/R22 spill lesson).
// ---------------------------------------------------------------------------
__global__ __launch_bounds__(256) void k1a_store(
    const float* __restrict__ feat,
    const short* __restrict__ Whi,
    const float* __restrict__ bs, const float* __restrict__ bi,
    const float* __restrict__ br,
    float* __restrict__ SpartT,          // 768 * G1GRID, transposed
    unsigned short* __restrict__ Pb,     // 3*N*128 bf16
    int N, int ntiles)
{
  __shared__ short Ah[32 * LDA];   // 8.7 KB

  const int tid  = threadIdx.x;
  const int lane = tid & 63;
  const int wv   = tid >> 6;          // 0..3
  const int l15  = lane & 15;
  const int kg   = lane >> 4;         // 0..3
  const int krow = kg * 8;
  const int sr   = tid >> 3;          // staging row 0..31
  const int so   = tid & 7;           // staging 16-float chunk

  const int col0 = wv * 32 + l15;
  const int col1 = wv * 32 + 16 + l15;

  float bias0[3], bias1[3];
  {
    const float* Bm[3] = {bs, bi, br};
#pragma unroll
    for (int m = 0; m < 3; m++) { bias0[m] = Bm[m][col0]; bias1[m] = Bm[m][col1]; }
  }
  float ssum0[3] = {0.f, 0.f, 0.f}, ssq0[3] = {0.f, 0.f, 0.f};
  float ssum1[3] = {0.f, 0.f, 0.f}, ssq1[3] = {0.f, 0.f, 0.f};
  const size_t nf = (size_t)N * NFEAT;

  for (int tile = blockIdx.x; tile < ntiles; tile += gridDim.x) {
    const int row0 = tile * 32;
    // ---- stage 32x128 tile as bf16
    {
      int gr = row0 + sr; if (gr >= N) gr = N - 1;
      const float4* s4 = (const float4*)(feat + (size_t)gr * NFEAT + so * 16);
      short hbuf[16];
#pragma unroll
      for (int q = 0; q < 4; q++) {
        float4 f = s4[q];
        float xs[4] = {f.x, f.y, f.z, f.w};
#pragma unroll
        for (int cc = 0; cc < 4; cc++) hbuf[q * 4 + cc] = (short)f2bf(xs[cc]);
      }
      *(short8*)&Ah[sr * LDA + so * 16]     = *(short8*)(hbuf);
      *(short8*)&Ah[sr * LDA + so * 16 + 8] = *(short8*)(hbuf + 8);
    }
    asm volatile("s_waitcnt lgkmcnt(0)" ::: "memory");
    __builtin_amdgcn_s_barrier();

    // ---- m-outer compute: 4 live accs, 48 MFMA/tile/wave
#pragma unroll
    for (int m = 0; m < 3; m++) {
      f32x4 a00 = {0.f,0.f,0.f,0.f}, a01 = {0.f,0.f,0.f,0.f};
      f32x4 a10 = {0.f,0.f,0.f,0.f}, a11 = {0.f,0.f,0.f,0.f};
#pragma unroll
      for (int kf = 0; kf < 4; kf++) {
        int fb0 = ((m * 16 + kf * 4 + kg) << 10) + (col0 << 3);
        int fb1 = ((m * 16 + kf * 4 + kg) << 10) + (col1 << 3);
        short8 b0 = *(const short8*)&Whi[fb0];
        short8 b1 = *(const short8*)&Whi[fb1];
        short8 ar0 = *(const short8*)&Ah[(l15) * LDA + kf * 32 + krow];
        short8 ar1 = *(const short8*)&Ah[(16 + l15) * LDA + kf * 32 + krow];
        a00 = __builtin_amdgcn_mfma_f32_16x16x32_bf16(ar0, b0, a00, 0, 0, 0);
        a01 = __builtin_amdgcn_mfma_f32_16x16x32_bf16(ar1, b0, a01, 0, 0, 0);
        a10 = __builtin_amdgcn_mfma_f32_16x16x32_bf16(ar0, b1, a10, 0, 0, 0);
        a11 = __builtin_amdgcn_mfma_f32_16x16x32_bf16(ar1, b1, a11, 0, 0, 0);
      }
      // epilogue for this m: bias, stats, bf16 store
#pragma unroll
      for (int g = 0; g < 4; g++) {
        int gr0 = row0 + kg * 4 + g;        // rf = 0
        int gr1 = row0 + 16 + kg * 4 + g;   // rf = 1
        if (gr0 < N) {
          float v = a00[g] + bias0[m];
          ssum0[m] += v; ssq0[m] += v * v;
          Pb[(size_t)m * nf + (size_t)gr0 * NFEAT + col0] = f2bf(v);
          float w = a10[g] + bias1[m];
          ssum1[m] += w; ssq1[m] += w * w;
          Pb[(size_t)m * nf + (size_t)gr0 * NFEAT + col1] = f2bf(w);
        }
        if (gr1 < N) {
          float v = a01[g] + bias0[m];
          ssum0[m] += v; ssq0[m] += v * v;
          Pb[(size_t)m * nf + (size_t)gr1 * NFEAT + col0] = f2bf(v);
          float w = a11[g] + bias1[m];
          ssum1[m] += w; ssq1[m] += w * w;
          Pb[(size_t)m * nf + (size_t)gr1 * NFEAT + col1] = f2bf(w);
        }
      }
    }
    asm volatile("s_waitcnt lgkmcnt(0)" ::: "memory");
    __builtin_amdgcn_s_barrier();
  }

  // ---- reduce over kg, write transposed per-block partials
#pragma unroll
  for (int m = 0; m < 3; m++) {
    float s0 = ssum0[m], q0 = ssq0[m], s1 = ssum1[m], q1 = ssq1[m];
    s0 += __shfl_xor(s0, 16); s0 += __shfl_xor(s0, 32);
    q0 += __shfl_xor(q0, 16); q0 += __shfl_xor(q0, 32);
    s1 += __shfl_xor(s1, 16); s1 += __shfl_xor(s1, 32);
    q1 += __shfl_xor(q1, 16); q1 += __shfl_xor(q1, 32);
    if (kg == 0) {
      SpartT[(size_t)(m * 256 + col0) * G1GRID + blockIdx.x]       = s0;
      SpartT[(size_t)(m * 256 + 128 + col0) * G1GRID + blockIdx.x] = q0;
      SpartT[(size_t)(m * 256 + col1) * G1GRID + blockIdx.x]       = s1;
      SpartT[(size_t)(m * 256 + 128 + col1) * G1GRID + blockIdx.x] = q1;
    }
  }
}

// ---------------------------------------------------------------------------
// K_redbn: grid 384, one block per (m,c).  Two coalesced 1536-element
// reductions (sum + sumsq rows of SpartT), then BN fold + MT gather ->
// swizzled A4/B4 table entry.  Replaces k_red + k_bn + stats + memset.
//   A4[idx] = {MT1, MT2, MT3, a};  B4[idx] = {MTq1..3 (m==1 else 0), kv}
//   idx = m*128 + (c&7)*16 + (c>>3);  a = gamma*rsqrt(var+eps); kv = beta-a*mu.
// ---------------------------------------------------------------------------
__global__ __launch_bounds__(256) void k_redbn(
    const float* __restrict__ SpartT,
    const float* __restrict__ gamma, const float* __restrict__ beta,
    const float* __restrict__ MT,
    float4* __restrict__ A4, float4* __restrict__ B4, float invN)
{
  __shared__ float reds[8];
  const int tid = threadIdx.x;
  const int j = blockIdx.x;           // 0..383
  const int m = j >> 7, c = j & 127;
  const size_t rowS = (size_t)(m * 256 + c) * G1GRID;
  const size_t rowQ = (size_t)(m * 256 + 128 + c) * G1GRID;

  float s = 0.f, q = 0.f;
#pragma unroll
  for (int k = 0; k < G1GRID / 256; k++) {
    s += SpartT[rowS + k * 256 + tid];
    q += SpartT[rowQ + k * 256 + tid];
  }
#pragma unroll
  for (int off = 1; off < 64; off <<= 1) {
    s += __shfl_xor(s, off);
    q += __shfl_xor(q, off);
  }
  if ((tid & 63) == 0) { reds[tid >> 6] = s; reds[4 + (tid >> 6)] = q; }
  __syncthreads();
  if (tid == 0) {
    float sum = (reds[0] + reds[1]) + (reds[2] + reds[3]);
    float ssq = (reds[4] + reds[5]) + (reds[6] + reds[7]);
    float mu = sum * invN;
    float var = ssq * invN - mu * mu;
    float a = gamma[c] * rsqrtf(var + EPSBN);
    float kv = beta[c] - mu * a;
    int idx = m * 128 + (c & 7) * 16 + (c >> 3);
    A4[idx] = make_float4(MT[0 * 512 + m * 128 + c],
                          MT[1 * 512 + m * 128 + c],
                          MT[2 * 512 + m * 128 + c], a);
    if (m == 1)
      B4[idx] = make_float4(MT[0 * 512 + 384 + c],
                            MT[1 * 512 + 384 + c],
                            MT[2 * 512 + 384 + c], kv);
    else
      B4[idx] = make_float4(0.f, 0.f, 0.f, kv);
  }
}

// ---------------------------------------------------------------------------
// K1g: elementwise second-GEMM replacement.  Stages precomputed swizzled
// A4/B4 tables (384 coalesced float4 each — cheap startup, R21-proven).
// 16 lanes/row; per (row, m) one uint4 = 8 bf16 cols; conflict-free b128
// LDS table reads; v = relu(a*P+kv); branchless q-accum.  Zeroes logit3R.
// 256-thr block: >256 LDS staging via strided loops (R17 lesson).
// ---------------------------------------------------------------------------
__global__ __launch_bounds__(256) void k1g_post(
    const unsigned short* __restrict__ Pb,
    const float4* __restrict__ A4, const float4* __restrict__ B4,
    float* __restrict__ slogA, float* __restrict__ qv,
    float* __restrict__ logit3R, int N, int N4, int nrt)
{
  __shared__ float4 A4s[384];
  __shared__ float4 B4s[384];
  const int tid = threadIdx.x;
  for (int i = tid; i < 384; i += 256) { A4s[i] = A4[i]; B4s[i] = B4[i]; }
  __syncthreads();

  const int l15 = tid & 15;
  const int rg  = tid >> 4;
  const size_t nf = (size_t)N * NFEAT;

  for (int it = blockIdx.x; it < nrt; it += gridDim.x) {
    // zero logit3R for these 16 rows x NREP reps (128 float4; tid<128)
    if (tid < 128) {
      int rep = tid >> 4;
      int zr = it * 16 + (tid & 15);
      if (zr < N)
        *(float4*)&logit3R[(size_t)rep * N4 + (size_t)zr * 4] =
            make_float4(0.f, 0.f, 0.f, 0.f);
    }

    int row = it * 16 + rg;
    if (row >= N) continue;

    float s0 = 0.f, s1 = 0.f, s2 = 0.f;
    float q0 = 0.f, q1 = 0.f, q2 = 0.f;
#pragma unroll
    for (int m = 0; m < 3; m++) {
      const uint4* p4 =
          (const uint4*)(Pb + (size_t)m * nf + (size_t)row * NFEAT + l15 * 8);
      uint4 u = p4[0];
      unsigned dw[4] = {u.x, u.y, u.z, u.w};
#pragma unroll
      for (int d = 0; d < 4; d++) {
        {
          float4 ab = A4s[m * 128 + (2 * d) * 16 + l15];
          float4 bq = B4s[m * 128 + (2 * d) * 16 + l15];
          float P = bf2f((unsigned short)(dw[d] & 0xffffu));
          float v = fmaxf(fmaf(ab.w, P, bq.w), 0.f);
          s0 = fmaf(v, ab.x, s0); s1 = fmaf(v, ab.y, s1); s2 = fmaf(v, ab.z, s2);
          q0 = fmaf(v, bq.x, q0); q1 = fmaf(v, bq.y, q1); q2 = fmaf(v, bq.z, q2);
        }
        {
          float4 ab = A4s[m * 128 + (2 * d + 1) * 16 + l15];
          float4 bq = B4s[m * 128 + (2 * d + 1) * 16 + l15];
          float P = bf2f((unsigned short)(dw[d] >> 16));
          float v = fmaxf(fmaf(ab.w, P, bq.w), 0.f);
          s0 = fmaf(v, ab.x, s0); s1 = fmaf(v, ab.y, s1); s2 = fmaf(v, ab.z, s2);
          q0 = fmaf(v, bq.x, q0); q1 = fmaf(v, bq.y, q1); q2 = fmaf(v, bq.z, q2);
        }
      }
    }
#pragma unroll
    for (int off = 1; off < 16; off <<= 1) {
      s0 += __shfl_xor(s0, off); s1 += __shfl_xor(s1, off);
      s2 += __shfl_xor(s2, off);
      q0 += __shfl_xor(q0, off); q1 += __shfl_xor(q1, off);
      q2 += __shfl_xor(q2, off);
    }
    if (l15 == 0) {
      *(float4*)&slogA[(size_t)row * 4] = make_float4(s0, s1, s2, 0.f);
      *(float4*)&qv[(size_t)row * 4]    = make_float4(q0, q1, q2, 0.f);
    }
  }
}

// ---------------------------------------------------------------------------
// K_edge: 64 lanes = 21 edges x 3 comps; one atomic/lane, same-line merge,
// replica (waveID&7) spreads contention.
// ---------------------------------------------------------------------------
__global__ __launch_bounds__(256) void k_edge(
    const int* __restrict__ eidx, const float* __restrict__ ew,
    const float* __restrict__ q, float* __restrict__ logit3R,
    int E, int N4)
{
  const int wid  = (blockIdx.x * 256 + threadIdx.x) >> 6;
  const int lane = threadIdx.x & 63;
  const int el   = lane / 3;
  const int comp = lane - el * 3;
  if (el >= 21) return;
  const int e = wid * 21 + el;
  if (e >= E) return;

  int src = eidx[e];
  int dst = eidx[E + e];
  float w = ew[e];
  float qvv = q[(size_t)src * 4 + comp];
  int rep = wid & (NREP - 1);
  unsafeAtomicAdd(&logit3R[(size_t)rep * N4 + (size_t)dst * 4 + comp], qvv * w);
}

// ---------------------------------------------------------------------------
// K4t: out[r] = softmax(slog[r] + sum_rep logit3R[rep][r] + cb).
// ---------------------------------------------------------------------------
__global__ __launch_bounds__(256) void k4_final(
    const float* __restrict__ slogA, const float* __restrict__ logit3R,
    const float* __restrict__ cb,
    float* __restrict__ out, int N, int N4)
{
  int r = blockIdx.x * 256 + threadIdx.x;
  if (r >= N) return;
  float4 S = *(const float4*)&slogA[(size_t)r * 4];
  float l0 = S.x + cb[0], l1 = S.y + cb[1], l2 = S.z + cb[2];
#pragma unroll
  for (int rep = 0; rep < NREP; rep++) {
    float4 L = *(const float4*)&logit3R[(size_t)rep * N4 + (size_t)r * 4];
    l0 += L.x; l1 += L.y; l2 += L.z;
  }
  float mx = fmaxf(l0, fmaxf(l1, l2));
  float e0 = expf(l0 - mx), e1 = expf(l1 - mx), e2 = expf(l2 - mx);
  float inv = 1.f / (e0 + e1 + e2);
  out[(size_t)r * 3 + 0] = e0 * inv;
  out[(size_t)r * 3 + 1] = e1 * inv;
  out[(size_t)r * 3 + 2] = e2 * inv;
}

// ---------------------------------------------------------------------------
extern "C" void kernel_launch(void* const* d_in, const int* in_sizes, int n_in,
                              void* d_out, int out_size, void* d_ws, size_t ws_size,
                              hipStream_t stream)
{
  const float* feat  = (const float*)d_in[0];
  const int*   eidx  = (const int*)  d_in[1];
  const float* ew    = (const float*)d_in[2];
  const float* Ws    = (const float*)d_in[3];
  const float* bs    = (const float*)d_in[4];
  const float* Wi    = (const float*)d_in[5];
  const float* bi    = (const float*)d_in[6];
  const float* Wr    = (const float*)d_in[7];
  const float* br    = (const float*)d_in[8];
  const float* gamma = (const float*)d_in[9];
  const float* beta  = (const float*)d_in[10];
  const float* WtoI  = (const float*)d_in[11];
  const float* btoI  = (const float*)d_in[12];
  const float* WtoR  = (const float*)d_in[13];
  const float* btoR  = (const float*)d_in[14];
  const float* Wout  = (const float*)d_in[15];
  const float* bout  = (const float*)d_in[16];

  const int N = in_sizes[0] / NFEAT;
  const int E = in_sizes[2];
  const int N4 = 4 * N;
  const float invN = 1.0f / (float)N;
  float* out = (float*)d_out;

  float* logit3R = (float*)d_ws;                 // NREP*4*N
  float* slogA   = logit3R + (size_t)NREP * N4;  // 4*N
  float* qv      = slogA + 4 * (size_t)N;        // 4*N
  float* MT      = qv + 4 * (size_t)N;           // 1536
  float* cb      = MT + 1536;                    // 4
  float4* A4     = (float4*)(cb + 4 + 12);       // 384 float4 (pad to 16B)
  float4* B4     = A4 + 384;                     // 384 float4
  float* SpartT  = (float*)(B4 + 384);           // 768*G1GRID
  short* Whi     = (short*)(SpartT + (size_t)768 * G1GRID);  // 49152
  unsigned short* Pb = (unsigned short*)(Whi + 49152);       // 3*N*128 bf16

  const int nt32 = (N + 31) / 32;         // 3125
  const int nrt  = (N + 15) / 16;         // 6250

  kp_params<<<30, 256, 0, stream>>>(Ws, Wi, Wr, WtoI, btoI, WtoR, btoR,
                                    Wout, bout, Whi, MT, cb);
  k1a_store<<<G1GRID, 256, 0, stream>>>(feat, Whi, bs, bi, br, SpartT, Pb,
                                        N, nt32);
  k_redbn<<<384, 256, 0, stream>>>(SpartT, gamma, beta, MT, A4, B4, invN);
  k1g_post<<<2048, 256, 0, stream>>>(Pb, A4, B4, slogA, qv, logit3R,
                                     N, N4, nrt);
  const int nwaves = (E + 20) / 21;
  k_edge<<<(nwaves + 3) / 4, 256, 0, stream>>>(eidx, ew, qv, logit3R, E, N4);
  k4_final<<<(N + 255) / 256, 256, 0, stream>>>(slogA, logit3R, cb, out, N, N4);
}